// Round 21
// baseline (805.551 us; speedup 1.0000x reference)
//
#include <hip/hip_runtime.h>
#include <math.h>

typedef _Float16 h8 __attribute__((ext_vector_type(8)));
typedef float f4 __attribute__((ext_vector_type(4)));

#define BATCH 32768

__device__ __forceinline__ void gload16(const void* g, void* l) {
  __builtin_amdgcn_global_load_lds(
      (const __attribute__((address_space(1))) unsigned int*)g,
      (__attribute__((address_space(3))) unsigned int*)l, 16, 0, 0);
}

// ---------------- prep: input slices -> fp16, flat grid-stride, h8 stores ----------------
__global__ __launch_bounds__(256) void prep_input2_k(const float* __restrict__ in,
    _Float16* __restrict__ pose, _Float16* __restrict__ goal, _Float16* __restrict__ gate)
{
  const long long total = (long long)BATCH * 88;
  for (long long i = (long long)blockIdx.x * 256 + threadIdx.x; i < total;
       i += (long long)gridDim.x * 256) {
    const int b = (int)(i / 88);
    const int g = (int)(i % 88);
    const float* r = in + (size_t)b * 556;
    h8 v;
    if (g < 56) {
      const int c0 = g * 8;
      #pragma unroll
      for (int j = 0; j < 8; ++j) {
        const int c = c0 + j;
        v[j] = (_Float16)((c < 400) ? r[c] : (c == 400 ? 1.0f : 0.0f));
      }
      *reinterpret_cast<h8*>(pose + (size_t)b * 448 + c0) = v;
    } else if (g < 72) {
      const int c0 = (g - 56) * 8;
      #pragma unroll
      for (int j = 0; j < 8; ++j) {
        const int c = c0 + j;
        v[j] = (_Float16)((c < 78) ? r[400 + c] : (c == 78 ? 1.0f : 0.0f));
      }
      *reinterpret_cast<h8*>(goal + (size_t)b * 128 + c0) = v;
    } else {
      const int c0 = (g - 72) * 8;
      #pragma unroll
      for (int j = 0; j < 8; ++j) {
        const int c = c0 + j;
        v[j] = (_Float16)((c < 78) ? r[478 + c] : (c == 78 ? 1.0f : 0.0f));
      }
      *reinterpret_cast<h8*>(gate + (size_t)b * 128 + c0) = v;
    }
  }
}

// ---------------- merged prep: all 9 weight transposes in ONE launch ----------------
struct PrepDesc {
  const float* W;
  const float* bias;
  _Float16* out;
  int K, N, Nld, Kout, biasCols, biasLd;
  int tilesX, tiles;
};
struct PrepAll { PrepDesc d[9]; };

__global__ __launch_bounds__(256) void prep_wt_all_k(PrepAll p)
{
  __shared__ float tile[64 * 65];
  int bid = blockIdx.x;
  int i = 0;
  while (bid >= p.d[i].tiles) { bid -= p.d[i].tiles; ++i; }
  const PrepDesc& d = p.d[i];
  const int c0 = (bid % d.tilesX) * 64;
  const int n0 = (bid / d.tilesX) * 64;
  const int t = threadIdx.x;
  {
    const int nn = t & 63;
    #pragma unroll
    for (int q = 0; q < 16; ++q) {
      int cc = (t >> 6) + q * 4;
      int c = c0 + cc, n = n0 + nn;
      float v = 0.0f;
      if (n < d.N) {
        if (c < d.K) v = d.W[(size_t)c * d.Nld + n];
        else if (c - d.K < d.biasCols) v = d.bias[(size_t)(c - d.K) * d.biasLd + n];
      }
      tile[cc * 65 + nn] = v;
    }
  }
  __syncthreads();
  {
    const int cc = t & 63;
    #pragma unroll
    for (int q = 0; q < 16; ++q) {
      int nn = (t >> 6) + q * 4;
      d.out[(size_t)(n0 + nn) * d.Kout + c0 + cc] = (_Float16)tile[cc * 65 + nn];
    }
  }
}

// ---------------- multi-descriptor GEMM (128x128 tile, runtime bias, ELU fp16-out) ----
struct GDesc {
  const _Float16* A;
  const _Float16* Bw;
  _Float16* Out;
  const float* bias;
  int ldA, ldB, ldO, nChunks, tiles;
};
template<int ND>
struct GGroup { GDesc d[ND]; };

template<int ND>
__global__ __launch_bounds__(256, 2) void gemmM_k(GGroup<ND> g)
{
  __shared__ __align__(16) _Float16 As[2][128 * 64];
  __shared__ __align__(16) _Float16 Bs[2][128 * 64];

  int bid = blockIdx.x;
  int di = 0;
  while (di < ND - 1 && bid >= g.d[di].tiles) { bid -= g.d[di].tiles; ++di; }
  const GDesc& d = g.d[di];
  const int m0 = (bid & 255) * 128;
  const int n0 = (bid >> 8) * 128;
  const int ldA = d.ldA, ldB = d.ldB, ldO = d.ldO, nChunks = d.nChunks;

  const int t = threadIdx.x;
  const int wid = t >> 6;
  const int lane = t & 63;
  const int wm = (wid >> 1) * 64;
  const int wn = (wid & 1) * 64;
  const int lr = lane & 15;
  const int lg = lane >> 4;

  const int gr = lane >> 3;
  const int gcol = ((lane & 7) ^ gr) * 8;
  const _Float16* Abase = d.A + (size_t)(m0 + wid * 32 + gr) * ldA + gcol;
  const _Float16* Bbase = d.Bw + (size_t)(n0 + wid * 32 + gr) * ldB + gcol;

  f4 acc[4][4];
  #pragma unroll
  for (int i = 0; i < 4; ++i)
    #pragma unroll
    for (int j = 0; j < 4; ++j) { f4 z = {0.f, 0.f, 0.f, 0.f}; acc[i][j] = z; }

  auto issue = [&](int c, int buf) {
    #pragma unroll
    for (int i = 0; i < 4; ++i) {
      gload16(Abase + (size_t)(i * 8) * ldA + c * 64, &As[buf][(wid * 32 + i * 8) * 64]);
      gload16(Bbase + (size_t)(i * 8) * ldB + c * 64, &Bs[buf][(wid * 32 + i * 8) * 64]);
    }
  };

  auto mfma_step = [&](const _Float16* as, const _Float16* bs) {
    #pragma unroll
    for (int kk = 0; kk < 2; ++kk) {
      h8 af[4], bf[4];
      const int kslot = kk * 4 + lg;
      #pragma unroll
      for (int i = 0; i < 4; ++i) {
        const int row = wm + i * 16 + lr;
        af[i] = *reinterpret_cast<const h8*>(&as[row * 64 + ((kslot ^ (row & 7)) << 3)]);
      }
      #pragma unroll
      for (int j = 0; j < 4; ++j) {
        const int row = wn + j * 16 + lr;
        bf[j] = *reinterpret_cast<const h8*>(&bs[row * 64 + ((kslot ^ (row & 7)) << 3)]);
      }
      #pragma unroll
      for (int i = 0; i < 4; ++i)
        #pragma unroll
        for (int j = 0; j < 4; ++j)
          acc[i][j] = __builtin_amdgcn_mfma_f32_16x16x32_f16(af[i], bf[j], acc[i][j], 0, 0, 0);
    }
  };

  issue(0, 0);
  int cur = 0;
  for (int c = 0; c < nChunks; ++c) {
    __syncthreads();
    if (c + 1 < nChunks) issue(c + 1, cur ^ 1);
    mfma_step(As[cur], Bs[cur]);
    cur ^= 1;
  }

  #pragma unroll
  for (int j = 0; j < 4; ++j) {
    const int col = n0 + wn + j * 16 + lr;
    const float bvv = d.bias ? d.bias[col] : 0.0f;
    #pragma unroll
    for (int i = 0; i < 4; ++i) {
      const int rowb = m0 + wm + i * 16 + lg * 4;
      #pragma unroll
      for (int r = 0; r < 4; ++r) {
        float x = acc[i][j][r] + bvv;
        x = (x > 0.0f) ? x : expm1f(x);
        d.Out[(size_t)(rowb + r) * ldO + col] = (_Float16)x;
      }
    }
  }
}

// ---------------- plain GEMM (kept for g1): 128x128 tile ----------------
template<bool EPI_BIAS, bool DO_ELU, bool OUT_F32>
__global__ __launch_bounds__(256, 2) void gemm_k(
    const _Float16* __restrict__ A, const _Float16* __restrict__ Bw,
    void* __restrict__ OutP, const float* __restrict__ bias,
    int ldA, int ldB, int ldO, int nChunks, int nLimit)
{
  __shared__ __align__(16) _Float16 As[2][128 * 64];
  __shared__ __align__(16) _Float16 Bs[2][128 * 64];

  const int t = threadIdx.x;
  const int m0 = blockIdx.x * 128;
  const int n0 = blockIdx.y * 128;
  const int wid = t >> 6;
  const int lane = t & 63;
  const int wm = (wid >> 1) * 64;
  const int wn = (wid & 1) * 64;
  const int lr = lane & 15;
  const int lg = lane >> 4;

  const int gr = lane >> 3;
  const int gcol = ((lane & 7) ^ gr) * 8;
  const _Float16* Abase = A + (size_t)(m0 + wid * 32 + gr) * ldA + gcol;
  const _Float16* Bbase = Bw + (size_t)(n0 + wid * 32 + gr) * ldB + gcol;

  f4 acc[4][4];
  #pragma unroll
  for (int i = 0; i < 4; ++i)
    #pragma unroll
    for (int j = 0; j < 4; ++j) { f4 z = {0.f, 0.f, 0.f, 0.f}; acc[i][j] = z; }

  auto issue = [&](int c, int buf) {
    #pragma unroll
    for (int i = 0; i < 4; ++i) {
      gload16(Abase + (size_t)(i * 8) * ldA + c * 64, &As[buf][(wid * 32 + i * 8) * 64]);
      gload16(Bbase + (size_t)(i * 8) * ldB + c * 64, &Bs[buf][(wid * 32 + i * 8) * 64]);
    }
  };

  auto mfma_step = [&](const _Float16* as, const _Float16* bs) {
    #pragma unroll
    for (int kk = 0; kk < 2; ++kk) {
      h8 af[4], bf[4];
      const int kslot = kk * 4 + lg;
      #pragma unroll
      for (int i = 0; i < 4; ++i) {
        const int row = wm + i * 16 + lr;
        af[i] = *reinterpret_cast<const h8*>(&as[row * 64 + ((kslot ^ (row & 7)) << 3)]);
      }
      #pragma unroll
      for (int j = 0; j < 4; ++j) {
        const int row = wn + j * 16 + lr;
        bf[j] = *reinterpret_cast<const h8*>(&bs[row * 64 + ((kslot ^ (row & 7)) << 3)]);
      }
      #pragma unroll
      for (int i = 0; i < 4; ++i)
        #pragma unroll
        for (int j = 0; j < 4; ++j)
          acc[i][j] = __builtin_amdgcn_mfma_f32_16x16x32_f16(af[i], bf[j], acc[i][j], 0, 0, 0);
    }
  };

  issue(0, 0);
  int cur = 0;
  for (int c = 0; c < nChunks; ++c) {
    __syncthreads();
    if (c + 1 < nChunks) issue(c + 1, cur ^ 1);
    mfma_step(As[cur], Bs[cur]);
    cur ^= 1;
  }

  #pragma unroll
  for (int j = 0; j < 4; ++j) {
    const int col = n0 + wn + j * 16 + lr;
    if (col >= nLimit) continue;
    float bvv = 0.0f;
    if (EPI_BIAS) bvv = bias[col];
    #pragma unroll
    for (int i = 0; i < 4; ++i) {
      const int rowb = m0 + wm + i * 16 + lg * 4;
      #pragma unroll
      for (int r = 0; r < 4; ++r) {
        float x = acc[i][j][r] + bvv;
        if (DO_ELU) x = (x > 0.0f) ? x : expm1f(x);
        if (OUT_F32)
          reinterpret_cast<float*>(OutP)[(size_t)(rowb + r) * ldO + col] = x;
        else
          reinterpret_cast<_Float16*>(OutP)[(size_t)(rowb + r) * ldO + col] = (_Float16)x;
      }
    }
  }
}

// ---------------- expert GEMM (paired + 4 blocks/CU): 128x64 tile ----------
// Combines R19's expert-pairing (2 experts per barrier pair) with R14's 4-blocks/CU
// anti-phase. Wave w owns rows [w*32, w*32+32); tile N = 64 (one window/expert).
// Registers: acc[2][4]=32 + araw[2][2]=16 + temps ~50 -> fits 128/wave (4 waves/SIMD).
// LDS: Bs[2 buf][2 win][4096 el] (32KB) + wT[1280] = 34.8KB -> 4 blocks/CU.
// Grid 2048 blocks = exactly 2 rounds of 4/CU. 0-conflict swizzle throughout.
template<int KCe, bool DO_ELU, bool OUT_F32>
__global__ __launch_bounds__(256, 4) void expertH2_k(
    const _Float16* __restrict__ A, const _Float16* __restrict__ Bw,
    void* __restrict__ OutP, const _Float16* __restrict__ wpad,
    int ldA, int ldB, int ldO, int nLimit)
{
  constexpr int E = 10;
  constexpr int NP = E / 2;
  __shared__ __align__(16) _Float16 lds[16384 + 1280];
  _Float16* Bs = lds;
  _Float16* wT = lds + 16384;

  const int tid = threadIdx.x;
  const int w = tid >> 6;
  const int l = tid & 63;
  const int m0 = blockIdx.x * 128;
  const int n0 = blockIdx.y * 64;
  const int lr = l & 15;
  const int lg = l >> 4;

  // staging: thread -> row strow (0..31 per call), slot tid&7; source pre-swizzled
  const int strow = tid >> 3;
  const int scol = ((tid & 7) ^ (strow & 7)) * 8;

  auto stB = [&](int buf, int win, size_t colEl) {
    _Float16* d = Bs + buf * 8192 + win * 4096 + w * 512;
    const _Float16* sp = Bw + (size_t)(n0 + strow) * ldB + colEl + scol;
    gload16(sp, d);
    gload16(sp + (size_t)32 * ldB, d + 2048);
  };

  auto frag = [&](const _Float16* base, int row, int kslot) -> h8 {
    return *reinterpret_cast<const h8*>(base + row * 64 + ((kslot ^ (row & 7)) << 3));
  };

  h8 araw[2][2];
  auto loadA = [&](const _Float16* base, size_t ld, size_t col0) {
    #pragma unroll
    for (int kk = 0; kk < 2; ++kk)
      #pragma unroll
      for (int mi = 0; mi < 2; ++mi)
        araw[kk][mi] = *reinterpret_cast<const h8*>(
            base + (size_t)(m0 + w * 32 + mi * 16 + lr) * ld + col0 + (size_t)(kk * 4 + lg) * 8);
  };

  f4 acc[2][4];
  #pragma unroll
  for (int mi = 0; mi < 2; ++mi)
    #pragma unroll
    for (int ni = 0; ni < 4; ++ni) { f4 z = {0.f, 0.f, 0.f, 0.f}; acc[mi][ni] = z; }

  // ---- prologue: wT (transposed gate, 10x128) + A regs (kc=0) + B windows step 0 ----
  #pragma unroll
  for (int idx = tid; idx < 1280; idx += 256) {
    const int m = idx & 127, e = idx >> 7;
    wT[e * 128 + m] = wpad[(size_t)(m0 + m) * 64 + e];
  }
  loadA(A, (size_t)ldA, 0);
  stB(0, 0, 0);
  stB(0, 1, (size_t)KCe * 64);
  asm volatile("s_waitcnt vmcnt(0) lgkmcnt(0)" ::: "memory");
  __builtin_amdgcn_s_barrier();
  __builtin_amdgcn_sched_barrier(0);

  int s = 0;
  #pragma unroll 1
  for (int kc = 0; kc < KCe; ++kc) {
    #pragma unroll 1
    for (int p = 0; p < NP; ++p, ++s) {
      const _Float16* Bbuf = Bs + (s & 1) * 8192;
      const int nbuf = (s + 1) & 1;

      // ---- top: stage next step's window pair (or bias window) ----
      if (p + 1 < NP) {
        stB(nbuf, 0, (size_t)((2 * p + 2) * KCe + kc) * 64);
        stB(nbuf, 1, (size_t)((2 * p + 3) * KCe + kc) * 64);
      } else if (kc + 1 < KCe) {
        stB(nbuf, 0, (size_t)(kc + 1) * 64);
        stB(nbuf, 1, (size_t)(KCe + kc + 1) * 64);
      } else {
        stB(nbuf, 0, (size_t)(E * KCe) * 64);
      }
      __builtin_amdgcn_sched_barrier(0);

      // ---- MFMA: both experts of the pair (64 MFMA/wave, one barrier pair) ----
      #pragma unroll
      for (int sub = 0; sub < 2; ++sub) {
        const int e = 2 * p + sub;
        const _Float16* Bh = Bbuf + sub * 4096;
        _Float16 se[2];
        #pragma unroll
        for (int j = 0; j < 2; ++j) se[j] = wT[e * 128 + w * 32 + j * 16 + lr];
        #pragma unroll
        for (int kk = 0; kk < 2; ++kk) {
          h8 aa[2];
          #pragma unroll
          for (int mi = 0; mi < 2; ++mi) {
            h8 v = araw[kk][mi];
            const _Float16 sv = se[mi];
            #pragma unroll
            for (int q = 0; q < 8; ++q) v[q] = v[q] * sv;
            aa[mi] = v;
          }
          h8 bf[4];
          #pragma unroll
          for (int ni = 0; ni < 4; ++ni)
            bf[ni] = frag(Bh, ni * 16 + lr, kk * 4 + lg);
          __builtin_amdgcn_s_setprio(1);
          #pragma unroll
          for (int mi = 0; mi < 2; ++mi)
            #pragma unroll
            for (int ni = 0; ni < 4; ++ni)
              acc[mi][ni] =
                  __builtin_amdgcn_mfma_f32_16x16x32_f16(aa[mi], bf[ni], acc[mi][ni], 0, 0, 0);
          __builtin_amdgcn_s_setprio(0);
        }
      }

      // ---- bottom: next step's windows resident ----
      __builtin_amdgcn_sched_barrier(0);
      asm volatile("s_waitcnt vmcnt(0)" ::: "memory");
      __builtin_amdgcn_s_barrier();
      __builtin_amdgcn_sched_barrier(0);
    }
    // kc boundary: refresh A regs (amortized over NP steps)
    if (kc + 1 < KCe) loadA(A, (size_t)ldA, (size_t)(kc + 1) * 64);
    else              loadA(wpad, 64, 0);
  }

  // ---- bias step: single window (buf s&1, win 0), A = wpad frags, unscaled ----
  {
    const _Float16* Bh = Bs + (s & 1) * 8192;
    #pragma unroll
    for (int kk = 0; kk < 2; ++kk) {
      h8 bf[4];
      #pragma unroll
      for (int ni = 0; ni < 4; ++ni)
        bf[ni] = frag(Bh, ni * 16 + lr, kk * 4 + lg);
      #pragma unroll
      for (int mi = 0; mi < 2; ++mi)
        #pragma unroll
        for (int ni = 0; ni < 4; ++ni)
          acc[mi][ni] =
              __builtin_amdgcn_mfma_f32_16x16x32_f16(araw[kk][mi], bf[ni], acc[mi][ni], 0, 0, 0);
    }
  }

  // ---- epilogue ----
  #pragma unroll
  for (int ni = 0; ni < 4; ++ni) {
    const int col = n0 + ni * 16 + lr;
    if (col >= nLimit) continue;
    #pragma unroll
    for (int mi = 0; mi < 2; ++mi) {
      const int rowb = m0 + w * 32 + mi * 16 + lg * 4;
      #pragma unroll
      for (int r = 0; r < 4; ++r) {
        float x = acc[mi][ni][r];
        if (DO_ELU) x = (x > 0.0f) ? x : expm1f(x);
        if (OUT_F32)
          reinterpret_cast<float*>(OutP)[(size_t)(rowb + r) * ldO + col] = x;
        else
          reinterpret_cast<_Float16*>(OutP)[(size_t)(rowb + r) * ldO + col] = (_Float16)x;
      }
    }
  }
}

// ---------------- expert GEMM: 256x(NI*16) tile, A in regs, B ring-3 + counted vmcnt ----
template<int KCe, int NI, bool DO_ELU, bool OUT_F32>
__global__ __launch_bounds__(256, 2) void expertV_k(
    const _Float16* __restrict__ A, const _Float16* __restrict__ Bw,
    void* __restrict__ OutP, const _Float16* __restrict__ wpad,
    int ldA, int ldB, int ldO, int nLimit)
{
  constexpr int E = 10;
  constexpr int S = KCe * E + 1;
  constexpr int SG = NI / 2;
  constexpr int SLOT = NI * 1024;
  __shared__ __align__(16) _Float16 lds[3 * SLOT + 2560];
  _Float16* wT = lds + 3 * SLOT;

  const int tid = threadIdx.x;
  const int w = tid >> 6;
  const int l = tid & 63;
  const int m0 = blockIdx.x * 256;
  const int n0 = blockIdx.y * (NI * 16);
  const int lr = l & 15;
  const int lg = l >> 4;

  const int strow = tid >> 3;
  const int scol = ((tid & 7) ^ (strow & 7)) * 8;

  auto stB = [&](int slot, size_t colEl) {
    _Float16* d = lds + slot * SLOT + w * 512;
    const _Float16* sp = Bw + (size_t)(n0 + strow) * ldB + colEl + scol;
    #pragma unroll
    for (int p = 0; p < SG; ++p)
      gload16(sp + (size_t)(p * 32) * ldB, d + p * 2048);
  };

  auto frag = [&](const _Float16* base, int row, int kslot) -> h8 {
    return *reinterpret_cast<const h8*>(base + row * 64 + ((kslot ^ (row & 7)) << 3));
  };

  h8 araw[2][4];
  auto loadA = [&](const _Float16* base, size_t ld, size_t col0) {
    #pragma unroll
    for (int kk = 0; kk < 2; ++kk)
      #pragma unroll
      for (int mi = 0; mi < 4; ++mi)
        araw[kk][mi] = *reinterpret_cast<const h8*>(
            base + (size_t)(m0 + w * 64 + mi * 16 + lr) * ld + col0 + (size_t)(kk * 4 + lg) * 8);
  };

  f4 acc[4][NI];
  #pragma unroll
  for (int mi = 0; mi < 4; ++mi)
    #pragma unroll
    for (int ni = 0; ni < NI; ++ni) { f4 z = {0.f, 0.f, 0.f, 0.f}; acc[mi][ni] = z; }

  #pragma unroll
  for (int idx = tid; idx < 2560; idx += 256) {
    const int m = idx & 255, e = idx >> 8;
    wT[e * 256 + m] = wpad[(size_t)(m0 + m) * 64 + e];
  }
  loadA(A, (size_t)ldA, 0);
  stB(0, 0);
  stB(1, (size_t)KCe * 64);
  if constexpr (SG == 4) asm volatile("s_waitcnt vmcnt(4)" ::: "memory");
  else                   asm volatile("s_waitcnt vmcnt(5)" ::: "memory");
  asm volatile("s_waitcnt lgkmcnt(0)" ::: "memory");
  __builtin_amdgcn_s_barrier();
  __builtin_amdgcn_sched_barrier(0);

  int e_s = 0, kc_s = 0;
  int e_t = 2, kc_t = 0;
  #pragma unroll 1
  for (int s = 0; s < S; ++s) {
    const _Float16* Bh = lds + (s % 3) * SLOT;

    if (s + 2 < S) {
      const size_t col = (kc_t < KCe) ? (size_t)(e_t * KCe + kc_t) * 64
                                      : (size_t)(E * KCe) * 64;
      stB((s + 2) % 3, col);
    }
    __builtin_amdgcn_sched_barrier(0);

    const bool isBias = (kc_s == KCe);
    _Float16 se[4];
    if (!isBias) {
      #pragma unroll
      for (int j = 0; j < 4; ++j) se[j] = wT[e_s * 256 + w * 64 + j * 16 + lr];
    }

    #pragma unroll
    for (int kk = 0; kk < 2; ++kk) {
      h8 aa[4];
      #pragma unroll
      for (int mi = 0; mi < 4; ++mi) {
        h8 v = araw[kk][mi];
        if (!isBias) {
          const _Float16 sv = se[mi];
          #pragma unroll
          for (int q = 0; q < 8; ++q) v[q] = v[q] * sv;
        }
        aa[mi] = v;
      }
      #pragma unroll
      for (int c0 = 0; c0 < NI; c0 += 4) {
        h8 bf[4];
        #pragma unroll
        for (int ni = 0; ni < 4; ++ni)
          if (c0 + ni < NI) bf[ni] = frag(Bh, (c0 + ni) * 16 + lr, kk * 4 + lg);
        __builtin_amdgcn_s_setprio(1);
        #pragma unroll
        for (int mi = 0; mi < 4; ++mi)
          #pragma unroll
          for (int ni = 0; ni < 4; ++ni)
            if (c0 + ni < NI)
              acc[mi][c0 + ni] =
                  __builtin_amdgcn_mfma_f32_16x16x32_f16(aa[mi], bf[ni], acc[mi][c0 + ni], 0, 0, 0);
        __builtin_amdgcn_s_setprio(0);
      }
    }
    __builtin_amdgcn_sched_barrier(0);

    if (s + 1 < S) {
      if (s + 2 < S) {
        if constexpr (SG == 4) asm volatile("s_waitcnt vmcnt(4)" ::: "memory");
        else                   asm volatile("s_waitcnt vmcnt(5)" ::: "memory");
      } else {
        asm volatile("s_waitcnt vmcnt(0)" ::: "memory");
      }
      __builtin_amdgcn_s_barrier();
      __builtin_amdgcn_sched_barrier(0);
      if (e_s == E - 1) {
        if (kc_s + 1 < KCe) loadA(A, (size_t)ldA, (size_t)(kc_s + 1) * 64);
        else                loadA(wpad, 64, 0);
        e_s = 0; ++kc_s;
      } else ++e_s;
      if (kc_t < KCe) { if (e_t == E - 1) { e_t = 0; ++kc_t; } else ++e_t; }
    }
  }

  #pragma unroll
  for (int ni = 0; ni < NI; ++ni) {
    const int col = n0 + ni * 16 + lr;
    if (col >= nLimit) continue;
    #pragma unroll
    for (int mi = 0; mi < 4; ++mi) {
      const int rowb = m0 + w * 64 + mi * 16 + lg * 4;
      #pragma unroll
      for (int r = 0; r < 4; ++r) {
        float x = acc[mi][ni][r];
        if (DO_ELU) x = (x > 0.0f) ? x : expm1f(x);
        if (OUT_F32)
          reinterpret_cast<float*>(OutP)[(size_t)(rowb + r) * ldO + col] = x;
        else
          reinterpret_cast<_Float16*>(OutP)[(size_t)(rowb + r) * ldO + col] = (_Float16)x;
      }
    }
  }
}

// ---------------- gating final layer (N=10) + softmax -> wpad[B][64], 4 lanes/row ----------------
__global__ __launch_bounds__(256) void gate_softmax_k(const _Float16* __restrict__ gb,
    const float* __restrict__ W2, const float* __restrict__ b2, _Float16* __restrict__ wpad)
{
  __shared__ float W2s[5120];
  for (int i = threadIdx.x; i < 5120; i += 256) W2s[i] = W2[i];
  __syncthreads();
  const int t = threadIdx.x;
  const int sub = t & 3;
  const int b = blockIdx.x * 64 + (t >> 2);
  const _Float16* row = gb + (size_t)b * 512 + sub * 128;
  float acc[10];
  #pragma unroll
  for (int o = 0; o < 10; ++o) acc[o] = 0.0f;
  #pragma unroll 4
  for (int k0 = 0; k0 < 128; k0 += 8) {
    h8 x = *reinterpret_cast<const h8*>(row + k0);
    #pragma unroll
    for (int jj = 0; jj < 8; ++jj) {
      float xv = (float)x[jj];
      const int k = sub * 128 + k0 + jj;
      #pragma unroll
      for (int o = 0; o < 10; ++o) acc[o] += xv * W2s[k * 10 + o];
    }
  }
  #pragma unroll
  for (int o = 0; o < 10; ++o) {
    acc[o] += __shfl_xor(acc[o], 1);
    acc[o] += __shfl_xor(acc[o], 2);
    acc[o] += b2[o];
  }
  float mx = acc[0];
  #pragma unroll
  for (int o = 1; o < 10; ++o) mx = fmaxf(mx, acc[o]);
  float s = 0.0f;
  #pragma unroll
  for (int o = 0; o < 10; ++o) { acc[o] = expf(acc[o] - mx); s += acc[o]; }
  const float inv = 1.0f / s;
  h8 o0 = {0,0,0,0,0,0,0,0}, o1 = {0,0,0,0,0,0,0,0};
  if (sub == 0) {
    #pragma unroll
    for (int o = 0; o < 8; ++o) o0[o] = (_Float16)(acc[o] * inv);
    o1[0] = (_Float16)(acc[8] * inv);
    o1[1] = (_Float16)(acc[9] * inv);
  }
  _Float16* wr = wpad + (size_t)b * 64 + sub * 16;
  *reinterpret_cast<h8*>(wr) = o0;
  *reinterpret_cast<h8*>(wr + 8) = o1;
}

extern "C" void kernel_launch(void* const* d_in, const int* in_sizes, int n_in,
                              void* d_out, int out_size, void* d_ws, size_t ws_size,
                              hipStream_t stream)
{
  const float* input_ = (const float*)d_in[0];
  const float* e0_W0 = (const float*)d_in[1];
  const float* e0_b0 = (const float*)d_in[2];
  const float* e0_W1 = (const float*)d_in[3];
  const float* e0_b1 = (const float*)d_in[4];
  const float* e1_W0 = (const float*)d_in[5];
  const float* e1_b0 = (const float*)d_in[6];
  const float* e1_W1 = (const float*)d_in[7];
  const float* e1_b1 = (const float*)d_in[8];
  const float* g_W0  = (const float*)d_in[9];
  const float* g_b0  = (const float*)d_in[10];
  const float* g_W1  = (const float*)d_in[11];
  const float* g_b1  = (const float*)d_in[12];
  const float* g_W2  = (const float*)d_in[13];
  const float* g_b2  = (const float*)d_in[14];
  const float* m_W0  = (const float*)d_in[15];
  const float* m_b0  = (const float*)d_in[16];
  const float* m_W1  = (const float*)d_in[17];
  const float* m_b1  = (const float*)d_in[18];
  const float* m_W2  = (const float*)d_in[19];
  const float* m_b2  = (const float*)d_in[20];
  (void)in_sizes; (void)n_in; (void)out_size; (void)ws_size;

  char* ws = (char*)d_ws;
  size_t off = 0;
  auto alloc = [&](size_t bytes) { char* p = ws + off; off += (bytes + 255) & ~(size_t)255; return p; };

  const size_t Bn = BATCH;
  _Float16* wsA    = (_Float16*)alloc(Bn * 512 * 2);  // pose16[448] -> ga -> x1
  _Float16* wsB    = (_Float16*)alloc(Bn * 512 * 2);  // h0a -> gb
  _Float16* wsC    = (_Float16*)alloc(Bn * 640 * 2);  // feat -> x2
  _Float16* goal16 = (_Float16*)alloc(Bn * 128 * 2);
  _Float16* gate16 = (_Float16*)alloc(Bn * 128 * 2);
  _Float16* h1a16  = (_Float16*)alloc(Bn * 128 * 2);
  _Float16* wpad16 = (_Float16*)alloc(Bn * 64 * 2);
  _Float16* e0W0t  = (_Float16*)alloc((size_t)512 * 448 * 2);
  _Float16* e0W1t  = (_Float16*)alloc((size_t)512 * 512 * 2);
  _Float16* e1W0t  = (_Float16*)alloc((size_t)128 * 128 * 2);
  _Float16* e1W1t  = (_Float16*)alloc((size_t)128 * 128 * 2);
  _Float16* gW0t   = (_Float16*)alloc((size_t)512 * 128 * 2);
  _Float16* gW1t   = (_Float16*)alloc((size_t)512 * 512 * 2);
  _Float16* W0b    = (_Float16*)alloc((size_t)512 * 6464 * 2);
  _Float16* W1b    = (_Float16*)alloc((size_t)512 * 5184 * 2);
  _Float16* W2b    = (_Float16*)alloc((size_t)768 * 5184 * 2);

  dim3 blk(256);
  const int BIG = 1 << 30;

  prep_input2_k<<<dim3(2048), blk, 0, stream>>>(input_, wsA, goal16, gate16);

  // merged weight-transpose prep: one launch for all 9 matrices
  {
    PrepAll p;
    auto mk = [](const float* W, const float* bias, _Float16* out,
                 int K, int N, int Nld, int Kout, int biasCols, int biasLd,
                 int tx, int ty) {
      PrepDesc d; d.W = W; d.bias = bias; d.out = out; d.K = K; d.N = N; d.Nld = Nld;
      d.Kout = Kout; d.biasCols = biasCols; d.biasLd = biasLd; d.tilesX = tx; d.tiles = tx * ty;
      return d;
    };
    p.d[0] = mk(e0_W0, e0_b0, e0W0t, 400, 512, 512, 448, 1, 0, 7, 8);
    p.d[1] = mk(e0_W1, nullptr, e0W1t, 512, 512, 512, 512, 0, 0, 8, 8);
    p.d[2] = mk(e1_W0, e1_b0, e1W0t, 78, 128, 128, 128, 1, 0, 2, 2);
    p.d[3] = mk(e1_W1, nullptr, e1W1t, 128, 128, 128, 128, 0, 0, 2, 2);
    p.d[4] = mk(g_W0, g_b0, gW0t, 78, 512, 512, 128, 1, 0, 2, 8);
    p.d[5] = mk(g_W1, nullptr, gW1t, 512, 512, 512, 512, 0, 0, 8, 8);
    p.d[6] = mk(m_W0, m_b0, W0b, 6400, 512, 512, 6464, 10, 512, 101, 8);
    p.d[7] = mk(m_W1, m_b1, W1b, 5120, 512, 512, 5184, 10, 512, 81, 8);
    p.d[8] = mk(m_W2, m_b2, W2b, 5120, 578, 578, 5184, 10, 578, 81, 12);
    int total = 0;
    for (int i = 0; i < 9; ++i) total += p.d[i].tiles;
    prep_wt_all_k<<<dim3(total), blk, 0, stream>>>(p);
  }

  // ---- merged GEMM group 1: e0L0 (wsA->wsB) + e1L0 (goal->h1a) ----
  {
    GGroup<2> g;
    g.d[0] = { wsA,    e0W0t, wsB,   nullptr, 448, 448, 512, 7, 256 * 4 };
    g.d[1] = { goal16, e1W0t, h1a16, nullptr, 128, 128, 128, 2, 256 * 1 };
    gemmM_k<2><<<dim3(256 * 4 + 256), blk, 0, stream>>>(g);
  }
  // ---- merged GEMM group 2: g0 (gate->wsA) + e0L1 (wsB->wsC) + e1L1 (h1a->wsC+512) ----
  {
    GGroup<3> g;
    g.d[0] = { gate16, gW0t,  wsA,        nullptr, 128, 128, 512, 2, 256 * 4 };
    g.d[1] = { wsB,    e0W1t, wsC,        e0_b1,   512, 512, 640, 8, 256 * 4 };
    g.d[2] = { h1a16,  e1W1t, wsC + 512,  e1_b1,   128, 128, 640, 2, 256 * 1 };
    gemmM_k<3><<<dim3(256 * 4 + 256 * 4 + 256), blk, 0, stream>>>(g);
  }
  // gating layer 1: ga(wsA) -> gb(wsB)
  gemm_k<true, true, false><<<dim3(256, 4), blk, 0, stream>>>(
      wsA, gW1t, wsB, g_b1, 512, 512, 512, 8, BIG);
  gate_softmax_k<<<dim3(BATCH / 64), blk, 0, stream>>>(wsB, g_W2, g_b2, wpad16);

  // experts: feat(640) -> x1(512) -> x2(512) -> pred(578)
  // W0/W1: paired experts + 4 blocks/CU (128x64 tiles, 2048-block grid = 2 rounds)
  expertH2_k<10, true, false><<<dim3(256, 8), blk, 0, stream>>>(
      wsC, W0b, wsA, wpad16, 640, 6464, 512, BIG);
  expertH2_k<8, true, false><<<dim3(256, 8), blk, 0, stream>>>(
      wsA, W1b, wsC, wpad16, 512, 5184, 512, BIG);
  // W2: R13 expertV (NI=10, exact 512-block grid), ring-3 counted vmcnt
  expertV_k<8, 10, false, true><<<dim3(128, 4), blk, 0, stream>>>(
      wsC, W2b, d_out, wpad16, 512, 5184, 578, 578);
}

// Round 22
// 767.348 us; speedup vs baseline: 1.0498x; 1.0498x over previous
//
#include <hip/hip_runtime.h>
#include <math.h>

typedef _Float16 h8 __attribute__((ext_vector_type(8)));
typedef float f4 __attribute__((ext_vector_type(4)));

#define BATCH 32768

__device__ __forceinline__ void gload16(const void* g, void* l) {
  __builtin_amdgcn_global_load_lds(
      (const __attribute__((address_space(1))) unsigned int*)g,
      (__attribute__((address_space(3))) unsigned int*)l, 16, 0, 0);
}

// ---------------- prep: input slices -> fp16, flat grid-stride, h8 stores ----------------
__global__ __launch_bounds__(256) void prep_input2_k(const float* __restrict__ in,
    _Float16* __restrict__ pose, _Float16* __restrict__ goal, _Float16* __restrict__ gate)
{
  const long long total = (long long)BATCH * 88;
  for (long long i = (long long)blockIdx.x * 256 + threadIdx.x; i < total;
       i += (long long)gridDim.x * 256) {
    const int b = (int)(i / 88);
    const int g = (int)(i % 88);
    const float* r = in + (size_t)b * 556;
    h8 v;
    if (g < 56) {
      const int c0 = g * 8;
      #pragma unroll
      for (int j = 0; j < 8; ++j) {
        const int c = c0 + j;
        v[j] = (_Float16)((c < 400) ? r[c] : (c == 400 ? 1.0f : 0.0f));
      }
      *reinterpret_cast<h8*>(pose + (size_t)b * 448 + c0) = v;
    } else if (g < 72) {
      const int c0 = (g - 56) * 8;
      #pragma unroll
      for (int j = 0; j < 8; ++j) {
        const int c = c0 + j;
        v[j] = (_Float16)((c < 78) ? r[400 + c] : (c == 78 ? 1.0f : 0.0f));
      }
      *reinterpret_cast<h8*>(goal + (size_t)b * 128 + c0) = v;
    } else {
      const int c0 = (g - 72) * 8;
      #pragma unroll
      for (int j = 0; j < 8; ++j) {
        const int c = c0 + j;
        v[j] = (_Float16)((c < 78) ? r[478 + c] : (c == 78 ? 1.0f : 0.0f));
      }
      *reinterpret_cast<h8*>(gate + (size_t)b * 128 + c0) = v;
    }
  }
}

// ---------------- merged prep: all 9 weight transposes in ONE launch ----------------
struct PrepDesc {
  const float* W;
  const float* bias;
  _Float16* out;
  int K, N, Nld, Kout, biasCols, biasLd;
  int tilesX, tiles;
};
struct PrepAll { PrepDesc d[9]; };

__global__ __launch_bounds__(256) void prep_wt_all_k(PrepAll p)
{
  __shared__ float tile[64 * 65];
  int bid = blockIdx.x;
  int i = 0;
  while (bid >= p.d[i].tiles) { bid -= p.d[i].tiles; ++i; }
  const PrepDesc& d = p.d[i];
  const int c0 = (bid % d.tilesX) * 64;
  const int n0 = (bid / d.tilesX) * 64;
  const int t = threadIdx.x;
  {
    const int nn = t & 63;
    #pragma unroll
    for (int q = 0; q < 16; ++q) {
      int cc = (t >> 6) + q * 4;
      int c = c0 + cc, n = n0 + nn;
      float v = 0.0f;
      if (n < d.N) {
        if (c < d.K) v = d.W[(size_t)c * d.Nld + n];
        else if (c - d.K < d.biasCols) v = d.bias[(size_t)(c - d.K) * d.biasLd + n];
      }
      tile[cc * 65 + nn] = v;
    }
  }
  __syncthreads();
  {
    const int cc = t & 63;
    #pragma unroll
    for (int q = 0; q < 16; ++q) {
      int nn = (t >> 6) + q * 4;
      d.out[(size_t)(n0 + nn) * d.Kout + c0 + cc] = (_Float16)tile[cc * 65 + nn];
    }
  }
}

// ---------------- multi-descriptor GEMM (128x128 tile, runtime bias, ELU fp16-out) ----
struct GDesc {
  const _Float16* A;
  const _Float16* Bw;
  _Float16* Out;
  const float* bias;
  int ldA, ldB, ldO, nChunks, tiles;
};
template<int ND>
struct GGroup { GDesc d[ND]; };

template<int ND>
__global__ __launch_bounds__(256, 2) void gemmM_k(GGroup<ND> g)
{
  __shared__ __align__(16) _Float16 As[2][128 * 64];
  __shared__ __align__(16) _Float16 Bs[2][128 * 64];

  int bid = blockIdx.x;
  int di = 0;
  while (di < ND - 1 && bid >= g.d[di].tiles) { bid -= g.d[di].tiles; ++di; }
  const GDesc& d = g.d[di];
  const int m0 = (bid & 255) * 128;
  const int n0 = (bid >> 8) * 128;
  const int ldA = d.ldA, ldB = d.ldB, ldO = d.ldO, nChunks = d.nChunks;

  const int t = threadIdx.x;
  const int wid = t >> 6;
  const int lane = t & 63;
  const int wm = (wid >> 1) * 64;
  const int wn = (wid & 1) * 64;
  const int lr = lane & 15;
  const int lg = lane >> 4;

  const int gr = lane >> 3;
  const int gcol = ((lane & 7) ^ gr) * 8;
  const _Float16* Abase = d.A + (size_t)(m0 + wid * 32 + gr) * ldA + gcol;
  const _Float16* Bbase = d.Bw + (size_t)(n0 + wid * 32 + gr) * ldB + gcol;

  f4 acc[4][4];
  #pragma unroll
  for (int i = 0; i < 4; ++i)
    #pragma unroll
    for (int j = 0; j < 4; ++j) { f4 z = {0.f, 0.f, 0.f, 0.f}; acc[i][j] = z; }

  auto issue = [&](int c, int buf) {
    #pragma unroll
    for (int i = 0; i < 4; ++i) {
      gload16(Abase + (size_t)(i * 8) * ldA + c * 64, &As[buf][(wid * 32 + i * 8) * 64]);
      gload16(Bbase + (size_t)(i * 8) * ldB + c * 64, &Bs[buf][(wid * 32 + i * 8) * 64]);
    }
  };

  auto mfma_step = [&](const _Float16* as, const _Float16* bs) {
    #pragma unroll
    for (int kk = 0; kk < 2; ++kk) {
      h8 af[4], bf[4];
      const int kslot = kk * 4 + lg;
      #pragma unroll
      for (int i = 0; i < 4; ++i) {
        const int row = wm + i * 16 + lr;
        af[i] = *reinterpret_cast<const h8*>(&as[row * 64 + ((kslot ^ (row & 7)) << 3)]);
      }
      #pragma unroll
      for (int j = 0; j < 4; ++j) {
        const int row = wn + j * 16 + lr;
        bf[j] = *reinterpret_cast<const h8*>(&bs[row * 64 + ((kslot ^ (row & 7)) << 3)]);
      }
      #pragma unroll
      for (int i = 0; i < 4; ++i)
        #pragma unroll
        for (int j = 0; j < 4; ++j)
          acc[i][j] = __builtin_amdgcn_mfma_f32_16x16x32_f16(af[i], bf[j], acc[i][j], 0, 0, 0);
    }
  };

  issue(0, 0);
  int cur = 0;
  for (int c = 0; c < nChunks; ++c) {
    __syncthreads();
    if (c + 1 < nChunks) issue(c + 1, cur ^ 1);
    mfma_step(As[cur], Bs[cur]);
    cur ^= 1;
  }

  #pragma unroll
  for (int j = 0; j < 4; ++j) {
    const int col = n0 + wn + j * 16 + lr;
    const float bvv = d.bias ? d.bias[col] : 0.0f;
    #pragma unroll
    for (int i = 0; i < 4; ++i) {
      const int rowb = m0 + wm + i * 16 + lg * 4;
      #pragma unroll
      for (int r = 0; r < 4; ++r) {
        float x = acc[i][j][r] + bvv;
        x = (x > 0.0f) ? x : expm1f(x);
        d.Out[(size_t)(rowb + r) * ldO + col] = (_Float16)x;
      }
    }
  }
}

// ---------------- plain GEMM (kept for g1): 128x128 tile ----------------
template<bool EPI_BIAS, bool DO_ELU, bool OUT_F32>
__global__ __launch_bounds__(256, 2) void gemm_k(
    const _Float16* __restrict__ A, const _Float16* __restrict__ Bw,
    void* __restrict__ OutP, const float* __restrict__ bias,
    int ldA, int ldB, int ldO, int nChunks, int nLimit)
{
  __shared__ __align__(16) _Float16 As[2][128 * 64];
  __shared__ __align__(16) _Float16 Bs[2][128 * 64];

  const int t = threadIdx.x;
  const int m0 = blockIdx.x * 128;
  const int n0 = blockIdx.y * 128;
  const int wid = t >> 6;
  const int lane = t & 63;
  const int wm = (wid >> 1) * 64;
  const int wn = (wid & 1) * 64;
  const int lr = lane & 15;
  const int lg = lane >> 4;

  const int gr = lane >> 3;
  const int gcol = ((lane & 7) ^ gr) * 8;
  const _Float16* Abase = A + (size_t)(m0 + wid * 32 + gr) * ldA + gcol;
  const _Float16* Bbase = Bw + (size_t)(n0 + wid * 32 + gr) * ldB + gcol;

  f4 acc[4][4];
  #pragma unroll
  for (int i = 0; i < 4; ++i)
    #pragma unroll
    for (int j = 0; j < 4; ++j) { f4 z = {0.f, 0.f, 0.f, 0.f}; acc[i][j] = z; }

  auto issue = [&](int c, int buf) {
    #pragma unroll
    for (int i = 0; i < 4; ++i) {
      gload16(Abase + (size_t)(i * 8) * ldA + c * 64, &As[buf][(wid * 32 + i * 8) * 64]);
      gload16(Bbase + (size_t)(i * 8) * ldB + c * 64, &Bs[buf][(wid * 32 + i * 8) * 64]);
    }
  };

  auto mfma_step = [&](const _Float16* as, const _Float16* bs) {
    #pragma unroll
    for (int kk = 0; kk < 2; ++kk) {
      h8 af[4], bf[4];
      const int kslot = kk * 4 + lg;
      #pragma unroll
      for (int i = 0; i < 4; ++i) {
        const int row = wm + i * 16 + lr;
        af[i] = *reinterpret_cast<const h8*>(&as[row * 64 + ((kslot ^ (row & 7)) << 3)]);
      }
      #pragma unroll
      for (int j = 0; j < 4; ++j) {
        const int row = wn + j * 16 + lr;
        bf[j] = *reinterpret_cast<const h8*>(&bs[row * 64 + ((kslot ^ (row & 7)) << 3)]);
      }
      #pragma unroll
      for (int i = 0; i < 4; ++i)
        #pragma unroll
        for (int j = 0; j < 4; ++j)
          acc[i][j] = __builtin_amdgcn_mfma_f32_16x16x32_f16(af[i], bf[j], acc[i][j], 0, 0, 0);
    }
  };

  issue(0, 0);
  int cur = 0;
  for (int c = 0; c < nChunks; ++c) {
    __syncthreads();
    if (c + 1 < nChunks) issue(c + 1, cur ^ 1);
    mfma_step(As[cur], Bs[cur]);
    cur ^= 1;
  }

  #pragma unroll
  for (int j = 0; j < 4; ++j) {
    const int col = n0 + wn + j * 16 + lr;
    if (col >= nLimit) continue;
    float bvv = 0.0f;
    if (EPI_BIAS) bvv = bias[col];
    #pragma unroll
    for (int i = 0; i < 4; ++i) {
      const int rowb = m0 + wm + i * 16 + lg * 4;
      #pragma unroll
      for (int r = 0; r < 4; ++r) {
        float x = acc[i][j][r] + bvv;
        if (DO_ELU) x = (x > 0.0f) ? x : expm1f(x);
        if (OUT_F32)
          reinterpret_cast<float*>(OutP)[(size_t)(rowb + r) * ldO + col] = x;
        else
          reinterpret_cast<_Float16*>(OutP)[(size_t)(rowb + r) * ldO + col] = (_Float16)x;
      }
    }
  }
}

// ---------------- expert GEMM (paired steps): 256x128 tile, 2 experts per step ----------
template<int KCe, bool DO_ELU, bool OUT_F32>
__global__ __launch_bounds__(256, 2) void expertP2_k(
    const _Float16* __restrict__ A, const _Float16* __restrict__ Bw,
    void* __restrict__ OutP, const _Float16* __restrict__ wpad,
    int ldA, int ldB, int ldO, int nLimit)
{
  constexpr int E = 10;
  constexpr int NP = E / 2;
  __shared__ __align__(16) _Float16 lds[32768 + 2560];
  _Float16* Bs = lds;
  _Float16* wT = lds + 32768;

  const int tid = threadIdx.x;
  const int w = tid >> 6;
  const int l = tid & 63;
  const int m0 = blockIdx.x * 256;
  const int n0 = blockIdx.y * 128;
  const int lr = l & 15;
  const int lg = l >> 4;

  const int strow = tid >> 3;
  const int scol = ((tid & 7) ^ (strow & 7)) * 8;

  auto stB = [&](int buf, int win, size_t colEl) {
    _Float16* d = Bs + buf * 16384 + win * 8192 + w * 512;
    const _Float16* sp = Bw + (size_t)(n0 + strow) * ldB + colEl + scol;
    #pragma unroll
    for (int p = 0; p < 4; ++p)
      gload16(sp + (size_t)(p * 32) * ldB, d + p * 2048);
  };

  auto frag = [&](const _Float16* base, int row, int kslot) -> h8 {
    return *reinterpret_cast<const h8*>(base + row * 64 + ((kslot ^ (row & 7)) << 3));
  };

  h8 araw[2][4];
  auto loadA = [&](const _Float16* base, size_t ld, size_t col0) {
    #pragma unroll
    for (int kk = 0; kk < 2; ++kk)
      #pragma unroll
      for (int mi = 0; mi < 4; ++mi)
        araw[kk][mi] = *reinterpret_cast<const h8*>(
            base + (size_t)(m0 + w * 64 + mi * 16 + lr) * ld + col0 + (size_t)(kk * 4 + lg) * 8);
  };

  f4 acc[4][8];
  #pragma unroll
  for (int mi = 0; mi < 4; ++mi)
    #pragma unroll
    for (int ni = 0; ni < 8; ++ni) { f4 z = {0.f, 0.f, 0.f, 0.f}; acc[mi][ni] = z; }

  #pragma unroll
  for (int idx = tid; idx < 2560; idx += 256) {
    const int m = idx & 255, e = idx >> 8;
    wT[e * 256 + m] = wpad[(size_t)(m0 + m) * 64 + e];
  }
  loadA(A, (size_t)ldA, 0);
  stB(0, 0, 0);
  stB(0, 1, (size_t)KCe * 64);
  asm volatile("s_waitcnt vmcnt(0) lgkmcnt(0)" ::: "memory");
  __builtin_amdgcn_s_barrier();
  __builtin_amdgcn_sched_barrier(0);

  int s = 0;
  #pragma unroll 1
  for (int kc = 0; kc < KCe; ++kc) {
    #pragma unroll 1
    for (int p = 0; p < NP; ++p, ++s) {
      const _Float16* Bbuf = Bs + (s & 1) * 16384;
      const int nbuf = (s + 1) & 1;

      if (p + 1 < NP) {
        stB(nbuf, 0, (size_t)((2 * p + 2) * KCe + kc) * 64);
        stB(nbuf, 1, (size_t)((2 * p + 3) * KCe + kc) * 64);
      } else if (kc + 1 < KCe) {
        stB(nbuf, 0, (size_t)(kc + 1) * 64);
        stB(nbuf, 1, (size_t)(KCe + kc + 1) * 64);
      } else {
        stB(nbuf, 0, (size_t)(E * KCe) * 64);
      }
      __builtin_amdgcn_sched_barrier(0);

      #pragma unroll
      for (int sub = 0; sub < 2; ++sub) {
        const int e = 2 * p + sub;
        const _Float16* Bh = Bbuf + sub * 8192;
        _Float16 se[4];
        #pragma unroll
        for (int j = 0; j < 4; ++j) se[j] = wT[e * 256 + w * 64 + j * 16 + lr];
        #pragma unroll
        for (int kk = 0; kk < 2; ++kk) {
          h8 aa[4];
          #pragma unroll
          for (int mi = 0; mi < 4; ++mi) {
            h8 v = araw[kk][mi];
            const _Float16 sv = se[mi];
            #pragma unroll
            for (int q = 0; q < 8; ++q) v[q] = v[q] * sv;
            aa[mi] = v;
          }
          #pragma unroll
          for (int c0 = 0; c0 < 8; c0 += 4) {
            h8 bf[4];
            #pragma unroll
            for (int ni = 0; ni < 4; ++ni)
              bf[ni] = frag(Bh, (c0 + ni) * 16 + lr, kk * 4 + lg);
            __builtin_amdgcn_s_setprio(1);
            #pragma unroll
            for (int mi = 0; mi < 4; ++mi)
              #pragma unroll
              for (int ni = 0; ni < 4; ++ni)
                acc[mi][c0 + ni] =
                    __builtin_amdgcn_mfma_f32_16x16x32_f16(aa[mi], bf[ni], acc[mi][c0 + ni], 0, 0, 0);
            __builtin_amdgcn_s_setprio(0);
          }
        }
      }

      __builtin_amdgcn_sched_barrier(0);
      asm volatile("s_waitcnt vmcnt(0)" ::: "memory");
      __builtin_amdgcn_s_barrier();
      __builtin_amdgcn_sched_barrier(0);
    }
    if (kc + 1 < KCe) loadA(A, (size_t)ldA, (size_t)(kc + 1) * 64);
    else              loadA(wpad, 64, 0);
  }

  {
    const _Float16* Bh = Bs + (s & 1) * 16384;
    #pragma unroll
    for (int kk = 0; kk < 2; ++kk) {
      #pragma unroll
      for (int c0 = 0; c0 < 8; c0 += 4) {
        h8 bf[4];
        #pragma unroll
        for (int ni = 0; ni < 4; ++ni)
          bf[ni] = frag(Bh, (c0 + ni) * 16 + lr, kk * 4 + lg);
        #pragma unroll
        for (int mi = 0; mi < 4; ++mi)
          #pragma unroll
          for (int ni = 0; ni < 4; ++ni)
            acc[mi][c0 + ni] =
                __builtin_amdgcn_mfma_f32_16x16x32_f16(araw[kk][mi], bf[ni], acc[mi][c0 + ni], 0, 0, 0);
      }
    }
  }

  #pragma unroll
  for (int ni = 0; ni < 8; ++ni) {
    const int col = n0 + ni * 16 + lr;
    if (col >= nLimit) continue;
    #pragma unroll
    for (int mi = 0; mi < 4; ++mi) {
      const int rowb = m0 + w * 64 + mi * 16 + lg * 4;
      #pragma unroll
      for (int r = 0; r < 4; ++r) {
        float x = acc[mi][ni][r];
        if (DO_ELU) x = (x > 0.0f) ? x : expm1f(x);
        if (OUT_F32)
          reinterpret_cast<float*>(OutP)[(size_t)(rowb + r) * ldO + col] = x;
        else
          reinterpret_cast<_Float16*>(OutP)[(size_t)(rowb + r) * ldO + col] = (_Float16)x;
      }
    }
  }
}

// ---------------- expert GEMM: 256x(NI*16) tile, A in regs, B ring-3 + counted vmcnt ----
template<int KCe, int NI, bool DO_ELU, bool OUT_F32>
__global__ __launch_bounds__(256, 2) void expertV_k(
    const _Float16* __restrict__ A, const _Float16* __restrict__ Bw,
    void* __restrict__ OutP, const _Float16* __restrict__ wpad,
    int ldA, int ldB, int ldO, int nLimit)
{
  constexpr int E = 10;
  constexpr int S = KCe * E + 1;
  constexpr int SG = NI / 2;
  constexpr int SLOT = NI * 1024;
  __shared__ __align__(16) _Float16 lds[3 * SLOT + 2560];
  _Float16* wT = lds + 3 * SLOT;

  const int tid = threadIdx.x;
  const int w = tid >> 6;
  const int l = tid & 63;
  const int m0 = blockIdx.x * 256;
  const int n0 = blockIdx.y * (NI * 16);
  const int lr = l & 15;
  const int lg = l >> 4;

  const int strow = tid >> 3;
  const int scol = ((tid & 7) ^ (strow & 7)) * 8;

  auto stB = [&](int slot, size_t colEl) {
    _Float16* d = lds + slot * SLOT + w * 512;
    const _Float16* sp = Bw + (size_t)(n0 + strow) * ldB + colEl + scol;
    #pragma unroll
    for (int p = 0; p < SG; ++p)
      gload16(sp + (size_t)(p * 32) * ldB, d + p * 2048);
  };

  auto frag = [&](const _Float16* base, int row, int kslot) -> h8 {
    return *reinterpret_cast<const h8*>(base + row * 64 + ((kslot ^ (row & 7)) << 3));
  };

  h8 araw[2][4];
  auto loadA = [&](const _Float16* base, size_t ld, size_t col0) {
    #pragma unroll
    for (int kk = 0; kk < 2; ++kk)
      #pragma unroll
      for (int mi = 0; mi < 4; ++mi)
        araw[kk][mi] = *reinterpret_cast<const h8*>(
            base + (size_t)(m0 + w * 64 + mi * 16 + lr) * ld + col0 + (size_t)(kk * 4 + lg) * 8);
  };

  f4 acc[4][NI];
  #pragma unroll
  for (int mi = 0; mi < 4; ++mi)
    #pragma unroll
    for (int ni = 0; ni < NI; ++ni) { f4 z = {0.f, 0.f, 0.f, 0.f}; acc[mi][ni] = z; }

  #pragma unroll
  for (int idx = tid; idx < 2560; idx += 256) {
    const int m = idx & 255, e = idx >> 8;
    wT[e * 256 + m] = wpad[(size_t)(m0 + m) * 64 + e];
  }
  loadA(A, (size_t)ldA, 0);
  stB(0, 0);
  stB(1, (size_t)KCe * 64);
  if constexpr (SG == 4) asm volatile("s_waitcnt vmcnt(4)" ::: "memory");
  else                   asm volatile("s_waitcnt vmcnt(5)" ::: "memory");
  asm volatile("s_waitcnt lgkmcnt(0)" ::: "memory");
  __builtin_amdgcn_s_barrier();
  __builtin_amdgcn_sched_barrier(0);

  int e_s = 0, kc_s = 0;
  int e_t = 2, kc_t = 0;
  #pragma unroll 1
  for (int s = 0; s < S; ++s) {
    const _Float16* Bh = lds + (s % 3) * SLOT;

    if (s + 2 < S) {
      const size_t col = (kc_t < KCe) ? (size_t)(e_t * KCe + kc_t) * 64
                                      : (size_t)(E * KCe) * 64;
      stB((s + 2) % 3, col);
    }
    __builtin_amdgcn_sched_barrier(0);

    const bool isBias = (kc_s == KCe);
    _Float16 se[4];
    if (!isBias) {
      #pragma unroll
      for (int j = 0; j < 4; ++j) se[j] = wT[e_s * 256 + w * 64 + j * 16 + lr];
    }

    #pragma unroll
    for (int kk = 0; kk < 2; ++kk) {
      h8 aa[4];
      #pragma unroll
      for (int mi = 0; mi < 4; ++mi) {
        h8 v = araw[kk][mi];
        if (!isBias) {
          const _Float16 sv = se[mi];
          #pragma unroll
          for (int q = 0; q < 8; ++q) v[q] = v[q] * sv;
        }
        aa[mi] = v;
      }
      #pragma unroll
      for (int c0 = 0; c0 < NI; c0 += 4) {
        h8 bf[4];
        #pragma unroll
        for (int ni = 0; ni < 4; ++ni)
          if (c0 + ni < NI) bf[ni] = frag(Bh, (c0 + ni) * 16 + lr, kk * 4 + lg);
        __builtin_amdgcn_s_setprio(1);
        #pragma unroll
        for (int mi = 0; mi < 4; ++mi)
          #pragma unroll
          for (int ni = 0; ni < 4; ++ni)
            if (c0 + ni < NI)
              acc[mi][c0 + ni] =
                  __builtin_amdgcn_mfma_f32_16x16x32_f16(aa[mi], bf[ni], acc[mi][c0 + ni], 0, 0, 0);
        __builtin_amdgcn_s_setprio(0);
      }
    }
    __builtin_amdgcn_sched_barrier(0);

    if (s + 1 < S) {
      if (s + 2 < S) {
        if constexpr (SG == 4) asm volatile("s_waitcnt vmcnt(4)" ::: "memory");
        else                   asm volatile("s_waitcnt vmcnt(5)" ::: "memory");
      } else {
        asm volatile("s_waitcnt vmcnt(0)" ::: "memory");
      }
      __builtin_amdgcn_s_barrier();
      __builtin_amdgcn_sched_barrier(0);
      if (e_s == E - 1) {
        if (kc_s + 1 < KCe) loadA(A, (size_t)ldA, (size_t)(kc_s + 1) * 64);
        else                loadA(wpad, 64, 0);
        e_s = 0; ++kc_s;
      } else ++e_s;
      if (kc_t < KCe) { if (e_t == E - 1) { e_t = 0; ++kc_t; } else ++e_t; }
    }
  }

  #pragma unroll
  for (int ni = 0; ni < NI; ++ni) {
    const int col = n0 + ni * 16 + lr;
    if (col >= nLimit) continue;
    #pragma unroll
    for (int mi = 0; mi < 4; ++mi) {
      const int rowb = m0 + w * 64 + mi * 16 + lg * 4;
      #pragma unroll
      for (int r = 0; r < 4; ++r) {
        float x = acc[mi][ni][r];
        if (DO_ELU) x = (x > 0.0f) ? x : expm1f(x);
        if (OUT_F32)
          reinterpret_cast<float*>(OutP)[(size_t)(rowb + r) * ldO + col] = x;
        else
          reinterpret_cast<_Float16*>(OutP)[(size_t)(rowb + r) * ldO + col] = (_Float16)x;
      }
    }
  }
}

// ---------------- gating final layer (N=10) + softmax -> wpad[B][64], 4 lanes/row ----------------
__global__ __launch_bounds__(256) void gate_softmax_k(const _Float16* __restrict__ gb,
    const float* __restrict__ W2, const float* __restrict__ b2, _Float16* __restrict__ wpad)
{
  __shared__ float W2s[5120];
  for (int i = threadIdx.x; i < 5120; i += 256) W2s[i] = W2[i];
  __syncthreads();
  const int t = threadIdx.x;
  const int sub = t & 3;
  const int b = blockIdx.x * 64 + (t >> 2);
  const _Float16* row = gb + (size_t)b * 512 + sub * 128;
  float acc[10];
  #pragma unroll
  for (int o = 0; o < 10; ++o) acc[o] = 0.0f;
  #pragma unroll 4
  for (int k0 = 0; k0 < 128; k0 += 8) {
    h8 x = *reinterpret_cast<const h8*>(row + k0);
    #pragma unroll
    for (int jj = 0; jj < 8; ++jj) {
      float xv = (float)x[jj];
      const int k = sub * 128 + k0 + jj;
      #pragma unroll
      for (int o = 0; o < 10; ++o) acc[o] += xv * W2s[k * 10 + o];
    }
  }
  #pragma unroll
  for (int o = 0; o < 10; ++o) {
    acc[o] += __shfl_xor(acc[o], 1);
    acc[o] += __shfl_xor(acc[o], 2);
    acc[o] += b2[o];
  }
  float mx = acc[0];
  #pragma unroll
  for (int o = 1; o < 10; ++o) mx = fmaxf(mx, acc[o]);
  float s = 0.0f;
  #pragma unroll
  for (int o = 0; o < 10; ++o) { acc[o] = expf(acc[o] - mx); s += acc[o]; }
  const float inv = 1.0f / s;
  h8 o0 = {0,0,0,0,0,0,0,0}, o1 = {0,0,0,0,0,0,0,0};
  if (sub == 0) {
    #pragma unroll
    for (int o = 0; o < 8; ++o) o0[o] = (_Float16)(acc[o] * inv);
    o1[0] = (_Float16)(acc[8] * inv);
    o1[1] = (_Float16)(acc[9] * inv);
  }
  _Float16* wr = wpad + (size_t)b * 64 + sub * 16;
  *reinterpret_cast<h8*>(wr) = o0;
  *reinterpret_cast<h8*>(wr + 8) = o1;
}

extern "C" void kernel_launch(void* const* d_in, const int* in_sizes, int n_in,
                              void* d_out, int out_size, void* d_ws, size_t ws_size,
                              hipStream_t stream)
{
  const float* input_ = (const float*)d_in[0];
  const float* e0_W0 = (const float*)d_in[1];
  const float* e0_b0 = (const float*)d_in[2];
  const float* e0_W1 = (const float*)d_in[3];
  const float* e0_b1 = (const float*)d_in[4];
  const float* e1_W0 = (const float*)d_in[5];
  const float* e1_b0 = (const float*)d_in[6];
  const float* e1_W1 = (const float*)d_in[7];
  const float* e1_b1 = (const float*)d_in[8];
  const float* g_W0  = (const float*)d_in[9];
  const float* g_b0  = (const float*)d_in[10];
  const float* g_W1  = (const float*)d_in[11];
  const float* g_b1  = (const float*)d_in[12];
  const float* g_W2  = (const float*)d_in[13];
  const float* g_b2  = (const float*)d_in[14];
  const float* m_W0  = (const float*)d_in[15];
  const float* m_b0  = (const float*)d_in[16];
  const float* m_W1  = (const float*)d_in[17];
  const float* m_b1  = (const float*)d_in[18];
  const float* m_W2  = (const float*)d_in[19];
  const float* m_b2  = (const float*)d_in[20];
  (void)in_sizes; (void)n_in; (void)out_size; (void)ws_size;

  char* ws = (char*)d_ws;
  size_t off = 0;
  auto alloc = [&](size_t bytes) { char* p = ws + off; off += (bytes + 255) & ~(size_t)255; return p; };

  const size_t Bn = BATCH;
  _Float16* wsA    = (_Float16*)alloc(Bn * 512 * 2);  // pose16[448] -> ga -> x1
  _Float16* wsB    = (_Float16*)alloc(Bn * 512 * 2);  // h0a -> gb
  _Float16* wsC    = (_Float16*)alloc(Bn * 640 * 2);  // feat -> x2
  _Float16* goal16 = (_Float16*)alloc(Bn * 128 * 2);
  _Float16* gate16 = (_Float16*)alloc(Bn * 128 * 2);
  _Float16* h1a16  = (_Float16*)alloc(Bn * 128 * 2);
  _Float16* wpad16 = (_Float16*)alloc(Bn * 64 * 2);
  _Float16* e0W0t  = (_Float16*)alloc((size_t)512 * 448 * 2);
  _Float16* e0W1t  = (_Float16*)alloc((size_t)512 * 512 * 2);
  _Float16* e1W0t  = (_Float16*)alloc((size_t)128 * 128 * 2);
  _Float16* e1W1t  = (_Float16*)alloc((size_t)128 * 128 * 2);
  _Float16* gW0t   = (_Float16*)alloc((size_t)512 * 128 * 2);
  _Float16* gW1t   = (_Float16*)alloc((size_t)512 * 512 * 2);
  _Float16* W0b    = (_Float16*)alloc((size_t)512 * 6464 * 2);
  _Float16* W1b    = (_Float16*)alloc((size_t)512 * 5184 * 2);
  _Float16* W2b    = (_Float16*)alloc((size_t)768 * 5184 * 2);

  dim3 blk(256);
  const int BIG = 1 << 30;

  prep_input2_k<<<dim3(2048), blk, 0, stream>>>(input_, wsA, goal16, gate16);

  // merged weight-transpose prep: one launch for all 9 matrices
  {
    PrepAll p;
    auto mk = [](const float* W, const float* bias, _Float16* out,
                 int K, int N, int Nld, int Kout, int biasCols, int biasLd,
                 int tx, int ty) {
      PrepDesc d; d.W = W; d.bias = bias; d.out = out; d.K = K; d.N = N; d.Nld = Nld;
      d.Kout = Kout; d.biasCols = biasCols; d.biasLd = biasLd; d.tilesX = tx; d.tiles = tx * ty;
      return d;
    };
    p.d[0] = mk(e0_W0, e0_b0, e0W0t, 400, 512, 512, 448, 1, 0, 7, 8);
    p.d[1] = mk(e0_W1, nullptr, e0W1t, 512, 512, 512, 512, 0, 0, 8, 8);
    p.d[2] = mk(e1_W0, e1_b0, e1W0t, 78, 128, 128, 128, 1, 0, 2, 2);
    p.d[3] = mk(e1_W1, nullptr, e1W1t, 128, 128, 128, 128, 0, 0, 2, 2);
    p.d[4] = mk(g_W0, g_b0, gW0t, 78, 512, 512, 128, 1, 0, 2, 8);
    p.d[5] = mk(g_W1, nullptr, gW1t, 512, 512, 512, 512, 0, 0, 8, 8);
    p.d[6] = mk(m_W0, m_b0, W0b, 6400, 512, 512, 6464, 10, 512, 101, 8);
    p.d[7] = mk(m_W1, m_b1, W1b, 5120, 512, 512, 5184, 10, 512, 81, 8);
    p.d[8] = mk(m_W2, m_b2, W2b, 5120, 578, 578, 5184, 10, 578, 81, 12);
    int total = 0;
    for (int i = 0; i < 9; ++i) total += p.d[i].tiles;
    prep_wt_all_k<<<dim3(total), blk, 0, stream>>>(p);
  }

  // ---- merged GEMM group 1: e0L0 (wsA->wsB) + e1L0 (goal->h1a) ----
  {
    GGroup<2> g;
    g.d[0] = { wsA,    e0W0t, wsB,   nullptr, 448, 448, 512, 7, 256 * 4 };
    g.d[1] = { goal16, e1W0t, h1a16, nullptr, 128, 128, 128, 2, 256 * 1 };
    gemmM_k<2><<<dim3(256 * 4 + 256), blk, 0, stream>>>(g);
  }
  // ---- merged GEMM group 2: g0 (gate->wsA) + e0L1 (wsB->wsC) + e1L1 (h1a->wsC+512) ----
  {
    GGroup<3> g;
    g.d[0] = { gate16, gW0t,  wsA,        nullptr, 128, 128, 512, 2, 256 * 4 };
    g.d[1] = { wsB,    e0W1t, wsC,        e0_b1,   512, 512, 640, 8, 256 * 4 };
    g.d[2] = { h1a16,  e1W1t, wsC + 512,  e1_b1,   128, 128, 640, 2, 256 * 1 };
    gemmM_k<3><<<dim3(256 * 4 + 256 * 4 + 256), blk, 0, stream>>>(g);
  }
  // gating layer 1: ga(wsA) -> gb(wsB)
  gemm_k<true, true, false><<<dim3(256, 4), blk, 0, stream>>>(
      wsA, gW1t, wsB, g_b1, 512, 512, 512, 8, BIG);
  gate_softmax_k<<<dim3(BATCH / 64), blk, 0, stream>>>(wsB, g_W2, g_b2, wpad16);

  // experts: feat(640) -> x1(512) -> x2(512) -> pred(578)
  expertP2_k<10, true, false><<<dim3(128, 4), blk, 0, stream>>>(
      wsC, W0b, wsA, wpad16, 640, 6464, 512, BIG);
  expertP2_k<8, true, false><<<dim3(128, 4), blk, 0, stream>>>(
      wsA, W1b, wsC, wpad16, 512, 5184, 512, BIG);
  expertV_k<8, 10, false, true><<<dim3(128, 4), blk, 0, stream>>>(
      wsC, W2b, d_out, wpad16, 512, 5184, 578, 578);
}